// Round 4
// baseline (73.250 us; speedup 1.0000x reference)
//
#include <hip/hip_runtime.h>

// RegionProposal, fully fused single-block kernel (v2).
// decode 55296 anchors -> stable top-6000 by score -> greedy NMS (IoU>0.7) ->
// first 300 kept boxes zero-padded to [300,4] fp32.
//
// Round-4 changes vs round 3:
//  * Phases A (histogram) and C (compact) read cls as uint4 in two
//    register-batches of 7 loads -> global latency overlapped (round 3 issued
//    54 scalar dependent loads per pass: ~30us of pure latency).
//  * NMS: 384x384 lower-triangle suppression bitmask built fully in parallel
//    (no barriers), then greedy resolution is a bitmask ballot fixed-point on
//    wave 0 (no IoU in the serial path). Chunked NMS kept for the remainder
//    (cands 384..cs) and the pathological fallback.
//
// Key = (flip(logit)<<32) | idx: ascending u64 == descending logit, ties by
// ascending index == stable argsort(-sigmoid(logit)) (sigmoid monotone).
// Decode math identical to rounds 1-3 (absmax 0.0).

#define ADIM 9
#define NANCH 55296
#define HWSZ 6144
#define CH_U4 1536      // HWSZ/4
#define TOT_U4 13824    // 9 * CH_U4
#define TOPK 6000
#define OUTK 300
#define NBINS 16384
#define CAP 8192
#define SCAP 1024
#define LCAP 7168       // CAP - SCAP
#define RANK1 512
#define MROWS 384
#define MW 6            // MROWS/64
#define THR 0.7f

typedef unsigned long long u64;
typedef unsigned int u32;

__device__ __forceinline__ u32 flipu(u32 b) {
    u32 u = (b & 0x80000000u) ? ~b : (b | 0x80000000u);
    return ~u;                       // ascending result == descending float
}

__device__ __forceinline__ bool iou_gt(float4 a, float aa, float4 b, float ba) {
    float ix = fminf(a.z, b.z) - fmaxf(a.x, b.x);
    float iy = fminf(a.w, b.w) - fmaxf(a.y, b.y);
    float inter = fmaxf(ix, 0.f) * fmaxf(iy, 0.f);
    float uni = aa + ba - inter;
    return inter / fmaxf(uni, 1e-12f) > THR;
}

__device__ __forceinline__ float4 decode_box(const float* __restrict__ loc,
                                             const float* __restrict__ anc, u32 n) {
    u32 a = n % ADIM, hw = n / ADIM;
    float t0 = loc[(4 * a + 0) * HWSZ + hw];
    float t1 = loc[(4 * a + 1) * HWSZ + hw];
    float t2 = loc[(4 * a + 2) * HWSZ + hw];
    float t3 = loc[(4 * a + 3) * HWSZ + hw];
    float4 an = reinterpret_cast<const float4*>(anc)[n];
    float cx = t0 * an.z + an.x;
    float cy = t1 * an.w + an.y;
    float bw = expf(t2) * an.z;
    float bh = expf(t3) * an.w;
    return make_float4(fminf(fmaxf(cx - bw * 0.5f, 0.f), 1.f),
                       fminf(fmaxf(cy - bh * 0.5f, 0.f), 1.f),
                       fminf(fmaxf(cx + bw * 0.5f, 0.f), 1.f),
                       fminf(fmaxf(cy + bh * 0.5f, 0.f), 1.f));
}

__device__ __forceinline__ u64 sx64(u64 v, int m) {
    u32 lo = __shfl_xor((u32)(v & 0xffffffffu), m, 64);
    u32 hi = __shfl_xor((u32)(v >> 32), m, 64);
    return ((u64)hi << 32) | lo;
}

__device__ __forceinline__ u64 ce64(u64 v, int j, int lane, bool up) {
    u64 pv = sx64(v, j);
    u64 mn = (pv < v) ? pv : v;
    u64 mx = (pv < v) ? v : pv;
    return (((lane & j) == 0) == up) ? mn : mx;
}

__device__ __forceinline__ uint4 load_cls_u4(const float* __restrict__ cls, int i) {
    int ch = i / CH_U4;
    int e  = i - ch * CH_U4;
    return reinterpret_cast<const uint4*>(cls)[(2 * ch + 1) * CH_U4 + e];
}

// wave-aggregated candidate append (phase C)
__device__ __forceinline__ void append_cand(u32 fs, u32 n, u32 B1, u32 B2,
                                            u64* cand, u32* shu, int lane) {
    u32 bin = fs >> 18;
    bool inB2 = bin <= B2;
    bool tryS = inB2 && (bin <= B1);
    u64 key = ((u64)fs << 32) | n;
    u32 posS = SCAP;
    u64 mS = __ballot(tryS ? 1 : 0);
    if (mS) {
        int leader = __ffsll((unsigned long long)mS) - 1;
        u32 bb = 0;
        if (lane == leader) bb = atomicAdd(&shu[0], (u32)__popcll(mS));
        bb = __shfl(bb, leader, 64);
        if (tryS) {
            posS = bb + (u32)__popcll(mS & ((1ull << lane) - 1ull));
            if (posS < SCAP) cand[posS] = key;
        }
    }
    bool toL = inB2 && (!tryS || posS >= SCAP);
    u64 mL = __ballot(toL ? 1 : 0);
    if (mL) {
        int leader = __ffsll((unsigned long long)mL) - 1;
        u32 bb = 0;
        if (lane == leader) bb = atomicAdd(&shu[1], (u32)__popcll(mL));
        bb = __shfl(bb, leader, 64);
        if (toL) {
            u32 q = bb + (u32)__popcll(mL & ((1ull << lane) - 1ull));
            if (q < LCAP) cand[CAP - 1 - q] = key;
        }
    }
}

__global__ void __launch_bounds__(1024) k_mega(const float* __restrict__ cls,
                                               const float* __restrict__ loc,
                                               const float* __restrict__ anc,
                                               float4* __restrict__ out) {
    __shared__ u64 cand[CAP];          // 64 KB; aliased as u32 hist[16384] in A/B
    __shared__ float4 sbox[SCAP];      // 16 KB
    __shared__ float  sarea[SCAP];     // 4 KB
    __shared__ u64 smask[MROWS][MW];   // 18 KB suppression bitmask (lower tri)
    __shared__ float4 kept[OUTK];
    __shared__ float  karea[OUTK];
    __shared__ float4 cbox[64];
    __shared__ float  carea[64];
    __shared__ u64 supw[16];
    __shared__ u64 sbyp[1024];         // 8 KB
    __shared__ u32 wsum[16];
    __shared__ u32 shu[8];             // 0:cntS 1:cntL 2:B1 3:B2 4:kc 5:i0

    const int tid = threadIdx.x;
    const int wid = tid >> 6;
    const int lane = tid & 63;
    u32* hist = (u32*)cand;

    // ---- A: histogram (batched uint4 loads) ----
    for (int i = tid; i < NBINS; i += 1024) hist[i] = 0;
    if (tid < 8) shu[tid] = 0;
    __syncthreads();
    #pragma unroll
    for (int half = 0; half < 2; ++half) {
        uint4 buf[7];
        #pragma unroll
        for (int k = 0; k < 7; ++k) {
            int i = (half * 7 + k) * 1024 + tid;
            buf[k] = (i < TOT_U4) ? load_cls_u4(cls, i) : make_uint4(0u, 0u, 0u, 0u);
        }
        #pragma unroll
        for (int k = 0; k < 7; ++k) {
            int i = (half * 7 + k) * 1024 + tid;
            if (i < TOT_U4) {
                atomicAdd(&hist[flipu(buf[k].x) >> 18], 1u);
                atomicAdd(&hist[flipu(buf[k].y) >> 18], 1u);
                atomicAdd(&hist[flipu(buf[k].z) >> 18], 1u);
                atomicAdd(&hist[flipu(buf[k].w) >> 18], 1u);
            }
        }
    }
    __syncthreads();

    // ---- B: scan + cutoff bins (rank-512 -> B1, rank-6000 -> B2) ----
    {
        int b0 = tid * 16;
        u32 s = 0;
        #pragma unroll
        for (int b = 0; b < 16; ++b) s += hist[b0 + b];
        u32 x = s;
        #pragma unroll
        for (int d = 1; d < 64; d <<= 1) {
            u32 y = __shfl_up(x, (unsigned)d, 64);
            if (lane >= d) x += y;
        }
        if (lane == 63) wsum[wid] = x;
        __syncthreads();
        if (wid == 0) {
            u32 w = (lane < 16) ? wsum[lane] : 0u;
            #pragma unroll
            for (int d = 1; d < 16; d <<= 1) {
                u32 y = __shfl_up(w, (unsigned)d, 64);
                if (lane >= d) w += y;
            }
            if (lane < 16) wsum[lane] = w;
        }
        __syncthreads();
        u32 incl = x + (wid ? wsum[wid - 1] : 0u);
        u32 before = incl - s;
        if (before < RANK1 && incl >= RANK1) {
            u32 run = before;
            for (int b = 0; b < 16; ++b) {
                run += hist[b0 + b];
                if (run >= RANK1) { shu[2] = (u32)(b0 + b); break; }
            }
        }
        if (before < TOPK && incl >= TOPK) {
            u32 run = before;
            for (int b = 0; b < 16; ++b) {
                run += hist[b0 + b];
                if (run >= TOPK) { shu[3] = (u32)(b0 + b); break; }
            }
        }
    }
    __syncthreads();
    const u32 B1 = shu[2], B2 = shu[3];

    // ---- C: compact (batched loads + wave-aggregated appends) ----
    for (int i = tid; i < CAP; i += 1024) cand[i] = ~0ull;
    __syncthreads();
    #pragma unroll
    for (int half = 0; half < 2; ++half) {
        uint4 buf[7];
        #pragma unroll
        for (int k = 0; k < 7; ++k) {
            int i = (half * 7 + k) * 1024 + tid;
            buf[k] = (i < TOT_U4) ? load_cls_u4(cls, i) : make_uint4(0u, 0u, 0u, 0u);
        }
        #pragma unroll
        for (int k = 0; k < 7; ++k) {
            int i = (half * 7 + k) * 1024 + tid;
            // element i: channel a = i/CH_U4, vec index e = i%CH_U4,
            // components c -> hw = e*4+c, anchor n = hw*ADIM + a
            int ch = i / CH_U4;
            int e  = i - ch * CH_U4;
            bool v = (i < TOT_U4);
            u32 n0 = (u32)((e * 4 + 0) * ADIM + ch);
            u32 fx = v ? flipu(buf[k].x) : 0xFFFFFFFFu;
            u32 fy = v ? flipu(buf[k].y) : 0xFFFFFFFFu;
            u32 fz = v ? flipu(buf[k].z) : 0xFFFFFFFFu;
            u32 fw = v ? flipu(buf[k].w) : 0xFFFFFFFFu;
            append_cand(fx, n0 + 0 * ADIM, B1, B2, cand, shu, lane);
            append_cand(fy, n0 + 1 * ADIM, B1, B2, cand, shu, lane);
            append_cand(fz, n0 + 2 * ADIM, B1, B2, cand, shu, lane);
            append_cand(fw, n0 + 3 * ADIM, B1, B2, cand, shu, lane);
        }
    }
    __syncthreads();
    const u32 cs = shu[0], cl = shu[1];
    const bool fast = (cs <= SCAP);

    // ---- D: fast-path sort of 1024 slots, decode, suppression matrix ----
    if (fast) {
        {   // in-wave stages k=2..64 (no barriers)
            u64 v = cand[tid];
            #pragma unroll
            for (int k = 2; k <= 64; k <<= 1)
                #pragma unroll
                for (int j = k >> 1; j >= 1; j >>= 1)
                    v = ce64(v, j, lane, ((tid & k) == 0));
            cand[tid] = v;
        }
        __syncthreads();
        for (int k = 128; k <= SCAP; k <<= 1) {
            for (int j = k >> 1; j >= 64; j >>= 1) {
                if (tid < SCAP / 2) {
                    u32 i = ((tid & ~(j - 1)) << 1) | (tid & (j - 1));
                    u32 l = i | (u32)j;
                    bool up = ((i & (u32)k) == 0);
                    u64 x = cand[i], y = cand[l];
                    if ((x > y) == up) { cand[i] = y; cand[l] = x; }
                }
                __syncthreads();
            }
            {
                u64 v = cand[tid];
                bool up = (((wid * 64) & k) == 0);
                #pragma unroll
                for (int j = 32; j >= 1; j >>= 1) v = ce64(v, j, lane, up);
                cand[tid] = v;
            }
            __syncthreads();
        }
        // decode sorted S boxes + zero the suppression masks
        {
            u64 key = cand[tid];
            if ((u32)tid < cs) {
                float4 b = decode_box(loc, anc, (u32)key);
                sbox[tid] = b;
                sarea[tid] = (b.z - b.x) * (b.w - b.y);
            } else {
                sbox[tid] = make_float4(0.f, 0.f, 0.f, 0.f);
                sarea[tid] = 0.f;
            }
            for (int i = tid; i < MROWS * MW; i += 1024) ((u64*)smask)[i] = 0ull;
        }
        __syncthreads();

        // parallel suppression-matrix build: bit j of smask[row][w] (j<row)
        const u32 rowsv = cs < MROWS ? cs : MROWS;
        for (int t = tid; t < MROWS * MW; t += 1024) {
            int row = t / MW, w = t - row * MW;
            if (row < (int)rowsv) {
                int j0 = w * 64;
                int jmax = row < (w + 1) * 64 ? row : (w + 1) * 64;
                if (j0 < jmax) {
                    float4 b = sbox[row];
                    float ba = sarea[row];
                    u64 m = 0;
                    for (int j = j0; j < jmax; ++j)
                        if (iou_gt(b, ba, sbox[j], sarea[j])) m |= 1ull << (j - j0);
                    smask[row][w] = m;
                }
            }
        }
        __syncthreads();

        // serial greedy resolution on wave 0: pure bitmask fixed point
        if (wid == 0) {
            u32 kc = 0, nexti0 = 0;
            u64 K[MW];
            #pragma unroll
            for (int w = 0; w < MW; ++w) K[w] = 0ull;
            #pragma unroll
            for (int cw = 0; cw < MW; ++cw) {
                u32 i0 = (u32)cw * 64u;
                if (i0 < rowsv && kc < OUTK) {
                    u32 ci = i0 + (u32)lane;
                    bool valid = ci < rowsv;
                    u64 myw[MW];
                    #pragma unroll
                    for (int w = 0; w < MW; ++w) myw[w] = valid ? smask[ci][w] : 0ull;
                    u64 supk = 0;
                    #pragma unroll
                    for (int w = 0; w < MW; ++w) supk |= myw[w] & K[w];
                    bool ia = valid && (supk == 0ull);
                    u64 inch = myw[cw] & ((1ull << lane) - 1ull);
                    u64 A = __ballot(ia ? 1 : 0);
                    for (int it = 0; it < 64; ++it) {
                        bool na = ia && ((inch & A) == 0ull);
                        u64 A2 = __ballot(na ? 1 : 0);
                        if (A2 == A) break;
                        A = A2;
                    }
                    bool kp = (A >> lane) & 1;
                    u32 rank = (u32)__popcll(A & ((1ull << lane) - 1ull));
                    if (kp && kc + rank < OUTK) {
                        float4 c = sbox[ci];
                        kept[kc + rank] = c;
                        karea[kc + rank] = sarea[ci];
                        out[kc + rank] = c;
                    }
                    K[cw] = A;
                    kc += (u32)__popcll(A);
                    nexti0 = i0 + 64;
                }
            }
            if (lane == 0) {
                shu[4] = kc > OUTK ? OUTK : kc;
                shu[5] = nexti0;
            }
        }

        // chunked NMS over the remainder [nexti0, cs)
        const u32 limit = cs;
        while (true) {
            __syncthreads();
            u32 kc = shu[4], i0 = shu[5];
            if (kc >= OUTK || i0 >= limit) break;
            u32 ci = i0 + (u32)lane;
            bool valid = ci < limit;
            float4 c = sbox[valid ? ci : 0];
            float ca = sarea[valid ? ci : 0];

            bool sup = false;
            for (u32 j = (u32)wid; j < kc; j += 16)
                sup = sup || iou_gt(c, ca, kept[j], karea[j]);
            u64 bal = __ballot(sup ? 1 : 0);
            if (lane == 0) supw[wid] = bal;

            u64 sby = 0;
            u32 smax = 4u * wid + 4u; if (smax > 63u) smax = 63u;
            for (u32 s = 4u * wid + 1u; s <= smax; ++s) {
                u32 p = ((u32)lane + s) & 63u;
                if (p < (u32)lane && (i0 + p) < limit)
                    if (iou_gt(c, ca, sbox[i0 + p], sarea[i0 + p])) sby |= (1ull << p);
            }
            sbyp[wid * 64 + lane] = sby;
            __syncthreads();

            if (wid == 0) {
                u64 sup64 = 0, sbyfull = 0;
                #pragma unroll
                for (int w = 0; w < 16; ++w) { sup64 |= supw[w]; sbyfull |= sbyp[w * 64 + lane]; }
                bool ia = valid && !((sup64 >> lane) & 1);
                u64 A = __ballot(ia ? 1 : 0);
                for (int it = 0; it < 64; ++it) {
                    bool na = ia && ((sbyfull & A) == 0);
                    u64 A2 = __ballot(na ? 1 : 0);
                    if (A2 == A) break;
                    A = A2;
                }
                bool kp = (A >> lane) & 1;
                u32 rank = (u32)__popcll(A & ((1ull << lane) - 1ull));
                if (kp && kc + rank < OUTK) {
                    kept[kc + rank] = c; karea[kc + rank] = ca; out[kc + rank] = c;
                }
                if (lane == 0) {
                    u32 nk = kc + (u32)__popcll(A);
                    shu[4] = nk > OUTK ? OUTK : nk;
                    shu[5] = i0 + 64;
                }
            }
        }
    }

    // ---- Fallback: full 8192 sort + NMS w/ on-the-fly decode (rare) ----
    __syncthreads();
    const u32 kcF = shu[4];
    const u32 inL = cl < LCAP ? cl : LCAP;
    const u32 storedS = fast ? cs : SCAP;
    const u32 totalv = storedS + inL;
    const u32 limfb = totalv < TOPK ? totalv : TOPK;
    const u32 i0fb = fast ? cs : 0u;
    if (kcF < OUTK && i0fb < limfb) {
        for (int seg = wid; seg < CAP / 64; seg += 16) {
            u64 v = cand[seg * 64 + lane];
            #pragma unroll
            for (int k = 2; k <= 64; k <<= 1)
                #pragma unroll
                for (int j = k >> 1; j >= 1; j >>= 1)
                    v = ce64(v, j, lane, (((seg * 64 + lane) & k) == 0));
            cand[seg * 64 + lane] = v;
        }
        __syncthreads();
        for (int k = 128; k <= CAP; k <<= 1) {
            for (int j = k >> 1; j >= 64; j >>= 1) {
                for (u32 p = (u32)tid; p < CAP / 2; p += 1024) {
                    u32 i = ((p & ~(u32)(j - 1)) << 1) | (p & (u32)(j - 1));
                    u32 l = i | (u32)j;
                    bool up = ((i & (u32)k) == 0);
                    u64 x = cand[i], y = cand[l];
                    if ((x > y) == up) { cand[i] = y; cand[l] = x; }
                }
                __syncthreads();
            }
            for (int seg = wid; seg < CAP / 64; seg += 16) {
                u64 v = cand[seg * 64 + lane];
                bool up = (((seg * 64) & k) == 0);
                #pragma unroll
                for (int j = 32; j >= 1; j >>= 1) v = ce64(v, j, lane, up);
                cand[seg * 64 + lane] = v;
            }
            __syncthreads();
        }
        if (tid == 0) shu[5] = i0fb;
        while (true) {
            __syncthreads();
            u32 kc = shu[4], i0 = shu[5];
            if (kc >= OUTK || i0 >= limfb) break;
            if (wid == 0) {
                u32 ci = i0 + (u32)lane;
                u32 n = (ci < limfb) ? (u32)cand[ci] : 0u;
                float4 b = decode_box(loc, anc, n);
                cbox[lane] = b;
                carea[lane] = (b.z - b.x) * (b.w - b.y);
            }
            __syncthreads();
            u32 ci = i0 + (u32)lane;
            bool valid = ci < limfb;
            float4 c = cbox[lane];
            float ca = carea[lane];
            bool sup = false;
            for (u32 j = (u32)wid; j < kc; j += 16)
                sup = sup || iou_gt(c, ca, kept[j], karea[j]);
            u64 bal = __ballot(sup ? 1 : 0);
            if (lane == 0) supw[wid] = bal;
            u64 sby = 0;
            u32 smax = 4u * wid + 4u; if (smax > 63u) smax = 63u;
            for (u32 s = 4u * wid + 1u; s <= smax; ++s) {
                u32 p = ((u32)lane + s) & 63u;
                if (p < (u32)lane && (i0 + p) < limfb)
                    if (iou_gt(c, ca, cbox[p], carea[p])) sby |= (1ull << p);
            }
            sbyp[wid * 64 + lane] = sby;
            __syncthreads();
            if (wid == 0) {
                u64 sup64 = 0, sbyfull = 0;
                #pragma unroll
                for (int w = 0; w < 16; ++w) { sup64 |= supw[w]; sbyfull |= sbyp[w * 64 + lane]; }
                bool ia = valid && !((sup64 >> lane) & 1);
                u64 A = __ballot(ia ? 1 : 0);
                for (int it = 0; it < 64; ++it) {
                    bool na = ia && ((sbyfull & A) == 0);
                    u64 A2 = __ballot(na ? 1 : 0);
                    if (A2 == A) break;
                    A = A2;
                }
                bool kp = (A >> lane) & 1;
                u32 rank = (u32)__popcll(A & ((1ull << lane) - 1ull));
                if (kp && kc + rank < OUTK) {
                    kept[kc + rank] = c; karea[kc + rank] = ca; out[kc + rank] = c;
                }
                if (lane == 0) {
                    u32 nk = kc + (u32)__popcll(A);
                    shu[4] = nk > OUTK ? OUTK : nk;
                    shu[5] = i0 + 64;
                }
            }
        }
    }

    // ---- zero-pad ----
    __syncthreads();
    u32 kc = shu[4];
    for (u32 r = (u32)tid; r < OUTK; r += 1024)
        if (r >= kc) out[r] = make_float4(0.f, 0.f, 0.f, 0.f);
}

extern "C" void kernel_launch(void* const* d_in, const int* in_sizes, int n_in,
                              void* d_out, int out_size, void* d_ws, size_t ws_size,
                              hipStream_t stream) {
    const float* cls = (const float*)d_in[0];   // (1, 18, 64, 96)
    const float* loc = (const float*)d_in[1];   // (1, 36, 64, 96)
    const float* anc = (const float*)d_in[2];   // (55296, 4)
    k_mega<<<1, 1024, 0, stream>>>(cls, loc, anc, (float4*)d_out);
}